// Round 5
// baseline (4806.520 us; speedup 1.0000x reference)
//
#include <hip/hip_runtime.h>
#include <math.h>

#define BB 8
#define TT 1500
#define DD 512
#define HH 8
#define HDD 64
#define TSS 750
#define FFD 2048
#define CBN 1025
#define CDD 64

static constexpr int N1 = BB * TSS;   // 6000
static constexpr int N2 = BB * TT;    // 12000
static constexpr long OUT_LOSS = (long)N2 * DD;  // 6144000

// ---- workspace offsets (floats); peak usage 50,066,832 floats = 200.3 MB ----
static constexpr long OFF_SC     = 0;            // 18,432,000-float multiplexed region
static constexpr long OFF_FF1    = OFF_SC;       // 6000*2048 = 12,288,000 (MLP phase)
static constexpr long OFF_X0     = OFF_SC + 12288000;  // 3,072,000 (MLP phase)
static constexpr long OFF_H0     = OFF_SC + 15360000;  // 3,072,000 (h0, then x1)
// attention phase: scores = OFF_SC .. +18,000,000
// FFN phase: chunk buffer = OFF_SC .. +12,288,000
static constexpr long OFF_XQ     = 18432000;     // 384,000
static constexpr long OFF_CBP    = 18816000;     // 524,800
static constexpr long OFF_IDX    = 19340800;     // 6016 ints
static constexpr long OFF_COMMIT = 19346816;     // 16 floats
static constexpr long OFF_X2     = 19346832;     // 6,144,000 (x2, later x4 target)
static constexpr long OFF_H2     = 25490832;     // 6,144,000 (h2 -> o)
static constexpr long OFF_Q      = 31634832;     // 6,144,000 (q -> x3)
static constexpr long OFF_K      = 37778832;     // 6,144,000 (k -> h3)
static constexpr long OFF_V      = 43922832;     // 6,144,000
// end = 50,066,832

__device__ __forceinline__ float gelu_tanh(float x) {
    float t = tanhf(0.7978845608028654f * (x + 0.044715f * x * x * x));
    return 0.5f * x * (1.0f + t);
}

// ---------- LayerNorm-style kernels (block=128, row of 512 floats) ----------

__device__ __forceinline__ void row_reduce2_128(float& s, float& sq) {
    int tid = threadIdx.x;
    int lane = tid & 63, wid = tid >> 6;
    for (int off = 32; off > 0; off >>= 1) {
        s  += __shfl_down(s, off);
        sq += __shfl_down(sq, off);
    }
    __shared__ float ss[2], ssq[2];
    if (lane == 0) { ss[wid] = s; ssq[wid] = sq; }
    __syncthreads();
    s  = ss[0] + ss[1];
    sq = ssq[0] + ssq[1];
}

__global__ __launch_bounds__(128) void k_ds_ln(const float* __restrict__ embs,
                                               const float* __restrict__ g,
                                               const float* __restrict__ be,
                                               float* __restrict__ x0,
                                               float* __restrict__ h0) {
    int r = blockIdx.x;               // 0..5999
    int b = r / TSS, ts = r - b * TSS;
    const float* src = embs + ((long)(b * TT + 2 * ts)) * DD;
    int tid = threadIdx.x;
    float4 v = *(const float4*)(src + tid * 4);
    float s = v.x + v.y + v.z + v.w;
    float sq = v.x * v.x + v.y * v.y + v.z * v.z + v.w * v.w;
    row_reduce2_128(s, sq);
    float mean = s * (1.0f / DD);
    float var = sq * (1.0f / DD) - mean * mean;
    float rstd = rsqrtf(var + 1e-5f);
    float4 gv = *(const float4*)(g + tid * 4);
    float4 bv = *(const float4*)(be + tid * 4);
    *(float4*)(x0 + (long)r * DD + tid * 4) = v;
    float4 hv;
    hv.x = (v.x - mean) * rstd * gv.x + bv.x;
    hv.y = (v.y - mean) * rstd * gv.y + bv.y;
    hv.z = (v.z - mean) * rstd * gv.z + bv.z;
    hv.w = (v.w - mean) * rstd * gv.w + bv.w;
    *(float4*)(h0 + (long)r * DD + tid * 4) = hv;
}

__global__ __launch_bounds__(128) void k_sel_pos_ln(const float* __restrict__ cbp,
                                                    const int* __restrict__ idxp,
                                                    const int* __restrict__ mask,
                                                    const float* __restrict__ pos,
                                                    const float* __restrict__ g,
                                                    const float* __restrict__ be,
                                                    float* __restrict__ x2,
                                                    float* __restrict__ h2) {
    int r = blockIdx.x;               // b*1500 + t
    int b = r / TT, t = r - b * TT;
    int mv = mask[r];
    int code = mv ? idxp[b * TSS + (t >> 1)] : (CBN - 1);
    int tid = threadIdx.x;
    float4 cv = *(const float4*)(cbp + (long)code * DD + tid * 4);
    float4 pv = *(const float4*)(pos + (long)t * DD + tid * 4);
    float4 v;
    v.x = cv.x + pv.x; v.y = cv.y + pv.y; v.z = cv.z + pv.z; v.w = cv.w + pv.w;
    float s = v.x + v.y + v.z + v.w;
    float sq = v.x * v.x + v.y * v.y + v.z * v.z + v.w * v.w;
    row_reduce2_128(s, sq);
    float mean = s * (1.0f / DD);
    float var = sq * (1.0f / DD) - mean * mean;
    float rstd = rsqrtf(var + 1e-5f);
    float4 gv = *(const float4*)(g + tid * 4);
    float4 bv = *(const float4*)(be + tid * 4);
    *(float4*)(x2 + (long)r * DD + tid * 4) = v;
    float4 hv;
    hv.x = (v.x - mean) * rstd * gv.x + bv.x;
    hv.y = (v.y - mean) * rstd * gv.y + bv.y;
    hv.z = (v.z - mean) * rstd * gv.z + bv.z;
    hv.w = (v.w - mean) * rstd * gv.w + bv.w;
    *(float4*)(h2 + (long)r * DD + tid * 4) = hv;
}

__global__ __launch_bounds__(128) void k_ln(const float* __restrict__ xin,
                                            const float* __restrict__ g,
                                            const float* __restrict__ be,
                                            float* __restrict__ hout) {
    int r = blockIdx.x;
    int tid = threadIdx.x;
    float4 v = *(const float4*)(xin + (long)r * DD + tid * 4);
    float s = v.x + v.y + v.z + v.w;
    float sq = v.x * v.x + v.y * v.y + v.z * v.z + v.w * v.w;
    row_reduce2_128(s, sq);
    float mean = s * (1.0f / DD);
    float var = sq * (1.0f / DD) - mean * mean;
    float rstd = rsqrtf(var + 1e-5f);
    float4 gv = *(const float4*)(g + tid * 4);
    float4 bv = *(const float4*)(be + tid * 4);
    float4 hv;
    hv.x = (v.x - mean) * rstd * gv.x + bv.x;
    hv.y = (v.y - mean) * rstd * gv.y + bv.y;
    hv.z = (v.z - mean) * rstd * gv.z + bv.z;
    hv.w = (v.w - mean) * rstd * gv.w + bv.w;
    *(float4*)(hout + (long)r * DD + tid * 4) = hv;
}

__global__ __launch_bounds__(128) void k_ln_out(const float* __restrict__ xin,
                                                const float* __restrict__ g,
                                                const float* __restrict__ be,
                                                float* __restrict__ out,
                                                const float* __restrict__ commit) {
    int r = blockIdx.x;
    int tid = threadIdx.x;
    float4 v = *(const float4*)(xin + (long)r * DD + tid * 4);
    float s = v.x + v.y + v.z + v.w;
    float sq = v.x * v.x + v.y * v.y + v.z * v.z + v.w * v.w;
    row_reduce2_128(s, sq);
    float mean = s * (1.0f / DD);
    float var = sq * (1.0f / DD) - mean * mean;
    float rstd = rsqrtf(var + 1e-5f);
    float4 gv = *(const float4*)(g + tid * 4);
    float4 bv = *(const float4*)(be + tid * 4);
    float4 hv;
    hv.x = (v.x - mean) * rstd * gv.x + bv.x;
    hv.y = (v.y - mean) * rstd * gv.y + bv.y;
    hv.z = (v.z - mean) * rstd * gv.z + bv.z;
    hv.w = (v.w - mean) * rstd * gv.w + bv.w;
    *(float4*)(out + (long)r * DD + tid * 4) = hv;
    if (r == 0 && tid == 0) out[OUT_LOSS] = commit[0] * (1.0f / 384000.0f);
}

// ---------- fp32 tiled GEMM: C[M,N] = epi(A[M,K] @ B + bias, Res) ----------
// TRANSB=false: B is K x N row-major (ldb); TRANSB=true: B is N x K row-major.
// EPI: 0 = +bias(optional), 1 = gelu(+bias), 2 = +bias+Res
template <bool TRANSB, int EPI>
__global__ __launch_bounds__(256) void k_gemm(const float* __restrict__ A, int lda, long sAz,
                                              const float* __restrict__ Bm, int ldb, long sBz,
                                              const float* __restrict__ bias,
                                              const float* __restrict__ Res, int ldr,
                                              float* __restrict__ C, int ldc, long sCz,
                                              int M, int N, int K) {
    A  += (long)blockIdx.z * sAz;
    Bm += (long)blockIdx.z * sBz;
    C  += (long)blockIdx.z * sCz;

    const int bm = blockIdx.x * 128;
    const int bn = blockIdx.y * 128;
    const int tid = threadIdx.x;
    const int tx = tid & 15, ty = tid >> 4;

    __shared__ float Ast[16][128];  // [k][m]
    __shared__ float Bs[16][128];   // [k][n]

    float acc[8][8];
#pragma unroll
    for (int i = 0; i < 8; i++)
#pragma unroll
        for (int j = 0; j < 8; j++) acc[i][j] = 0.f;

    const int am = tid >> 1;          // 0..127
    const int ak = (tid & 1) * 8;     // 0 or 8

    for (int k0 = 0; k0 < K; k0 += 16) {
        // ---- A tile ----
        {
            int row = bm + am;
            float av[8];
            if (row < M && (k0 + ak + 7) < K) {
                float4 p0 = *(const float4*)(A + (long)row * lda + k0 + ak);
                float4 p1 = *(const float4*)(A + (long)row * lda + k0 + ak + 4);
                av[0] = p0.x; av[1] = p0.y; av[2] = p0.z; av[3] = p0.w;
                av[4] = p1.x; av[5] = p1.y; av[6] = p1.z; av[7] = p1.w;
            } else {
#pragma unroll
                for (int i = 0; i < 8; i++) {
                    int kk = k0 + ak + i;
                    av[i] = (row < M && kk < K) ? A[(long)row * lda + kk] : 0.f;
                }
            }
#pragma unroll
            for (int i = 0; i < 8; i++) Ast[ak + i][am] = av[i];
        }
        // ---- B tile ----
        if (!TRANSB) {
            int krow = tid >> 4;            // 0..15
            int n8 = (tid & 15) * 8;        // 0..120
            int kk = k0 + krow;
            int nn = bn + n8;
            float bvv[8];
            if (kk < K && (nn + 7) < N) {
                float4 p0 = *(const float4*)(Bm + (long)kk * ldb + nn);
                float4 p1 = *(const float4*)(Bm + (long)kk * ldb + nn + 4);
                bvv[0] = p0.x; bvv[1] = p0.y; bvv[2] = p0.z; bvv[3] = p0.w;
                bvv[4] = p1.x; bvv[5] = p1.y; bvv[6] = p1.z; bvv[7] = p1.w;
            } else {
#pragma unroll
                for (int i = 0; i < 8; i++)
                    bvv[i] = (kk < K && (nn + i) < N) ? Bm[(long)kk * ldb + nn + i] : 0.f;
            }
#pragma unroll
            for (int i = 0; i < 8; i++) Bs[krow][n8 + i] = bvv[i];
        } else {
            int row = bn + (tid >> 1);      // N index
            int kloc = (tid & 1) * 8;
            int kk8 = k0 + kloc;
            float bvv[8];
            if (row < N && (kk8 + 7) < K) {
                float4 p0 = *(const float4*)(Bm + (long)row * ldb + kk8);
                float4 p1 = *(const float4*)(Bm + (long)row * ldb + kk8 + 4);
                bvv[0] = p0.x; bvv[1] = p0.y; bvv[2] = p0.z; bvv[3] = p0.w;
                bvv[4] = p1.x; bvv[5] = p1.y; bvv[6] = p1.z; bvv[7] = p1.w;
            } else {
#pragma unroll
                for (int i = 0; i < 8; i++) {
                    int kk = kk8 + i;
                    bvv[i] = (row < N && kk < K) ? Bm[(long)row * ldb + kk] : 0.f;
                }
            }
#pragma unroll
            for (int i = 0; i < 8; i++) Bs[kloc + i][tid >> 1] = bvv[i];
        }
        __syncthreads();

#pragma unroll
        for (int k = 0; k < 16; k++) {
            float a[8], bb[8];
            float4 t0 = *(const float4*)&Ast[k][ty * 8];
            float4 t1 = *(const float4*)&Ast[k][ty * 8 + 4];
            a[0] = t0.x; a[1] = t0.y; a[2] = t0.z; a[3] = t0.w;
            a[4] = t1.x; a[5] = t1.y; a[6] = t1.z; a[7] = t1.w;
            float4 u0 = *(const float4*)&Bs[k][tx * 8];
            float4 u1 = *(const float4*)&Bs[k][tx * 8 + 4];
            bb[0] = u0.x; bb[1] = u0.y; bb[2] = u0.z; bb[3] = u0.w;
            bb[4] = u1.x; bb[5] = u1.y; bb[6] = u1.z; bb[7] = u1.w;
#pragma unroll
            for (int i = 0; i < 8; i++)
#pragma unroll
                for (int j = 0; j < 8; j++) acc[i][j] = fmaf(a[i], bb[j], acc[i][j]);
        }
        __syncthreads();
    }

    // ---- epilogue ----
#pragma unroll
    for (int i = 0; i < 8; i++) {
        int m = bm + ty * 8 + i;
        if (m >= M) continue;
        float vv[8];
#pragma unroll
        for (int j = 0; j < 8; j++) {
            int n = bn + tx * 8 + j;
            float val = acc[i][j];
            if (n < N) {
                if (bias) val += bias[n];
                if (EPI == 1) val = gelu_tanh(val);
                if (EPI == 2) val += Res[(long)m * ldr + n];
            }
            vv[j] = val;
        }
        int nbase = bn + tx * 8;
        if (nbase + 7 < N) {
            float4 o0, o1;
            o0.x = vv[0]; o0.y = vv[1]; o0.z = vv[2]; o0.w = vv[3];
            o1.x = vv[4]; o1.y = vv[5]; o1.z = vv[6]; o1.w = vv[7];
            *(float4*)(C + (long)m * ldc + nbase) = o0;
            *(float4*)(C + (long)m * ldc + nbase + 4) = o1;
        } else {
#pragma unroll
            for (int j = 0; j < 8; j++) {
                int n = nbase + j;
                if (n < N) C[(long)m * ldc + n] = vv[j];
            }
        }
    }
}

// ---------- VQ argmin (f64 accumulation) + commit loss ----------
__global__ __launch_bounds__(256) void k_vq(const float* __restrict__ xq,
                                            const float* __restrict__ cb,
                                            int* __restrict__ idx,
                                            float* __restrict__ commit) {
    __shared__ float xs[64];
    __shared__ double sd[256];
    __shared__ int si[256];
    int r = blockIdx.x, tid = threadIdx.x;
    if (tid < 64) xs[tid] = xq[(long)r * 64 + tid];
    __syncthreads();

    double bestd = 1e300;
    int bi = 0;
    for (int c = tid; c < CBN; c += 256) {
        const float* crow = cb + (long)c * 64;
        double sacc = 0.0;
#pragma unroll 8
        for (int d = 0; d < 64; d++) {
            float diff = xs[d] - crow[d];
            sacc = fma((double)diff, (double)diff, sacc);
        }
        if (sacc < bestd) { bestd = sacc; bi = c; }
    }
    sd[tid] = bestd;
    si[tid] = bi;
    __syncthreads();
    for (int off = 128; off > 0; off >>= 1) {
        if (tid < off) {
            if (sd[tid + off] < sd[tid] ||
                (sd[tid + off] == sd[tid] && si[tid + off] < si[tid])) {
                sd[tid] = sd[tid + off];
                si[tid] = si[tid + off];
            }
        }
        __syncthreads();
    }
    int win = si[0];
    if (tid == 0) idx[r] = win;
    if (tid < 64) {
        float diff = cb[(long)win * 64 + tid] - xs[tid];
        float sq = diff * diff;
        for (int off = 32; off > 0; off >>= 1) sq += __shfl_down(sq, off);
        if (tid == 0) atomicAdd(commit, sq);
    }
}

// ---------- row softmax over 1500 (block=256) ----------
__global__ __launch_bounds__(256) void k_softmax(float* __restrict__ S) {
    float* row = S + ((long)blockIdx.y * 1500 + blockIdx.x) * 1500;
    int tid = threadIdx.x;
    int lane = tid & 63, wid = tid >> 6;
    float v[6];
    float mx = -1e30f;
#pragma unroll
    for (int l = 0; l < 6; l++) {
        int j = tid + l * 256;
        v[l] = (j < 1500) ? row[j] : -1e30f;
        mx = fmaxf(mx, v[l]);
    }
    for (int off = 32; off > 0; off >>= 1) mx = fmaxf(mx, __shfl_down(mx, off));
    __shared__ float sm[4];
    if (lane == 0) sm[wid] = mx;
    __syncthreads();
    mx = fmaxf(fmaxf(sm[0], sm[1]), fmaxf(sm[2], sm[3]));

    float s = 0.f;
#pragma unroll
    for (int l = 0; l < 6; l++) {
        int j = tid + l * 256;
        float e = (j < 1500) ? expf(v[l] - mx) : 0.f;
        v[l] = e;
        s += e;
    }
    for (int off = 32; off > 0; off >>= 1) s += __shfl_down(s, off);
    __shared__ float ssum[4];
    if (lane == 0) ssum[wid] = s;
    __syncthreads();
    s = ssum[0] + ssum[1] + ssum[2] + ssum[3];
    float inv = 1.0f / s;
#pragma unroll
    for (int l = 0; l < 6; l++) {
        int j = tid + l * 256;
        if (j < 1500) row[j] = v[l] * inv;
    }
}

extern "C" void kernel_launch(void* const* d_in, const int* in_sizes, int n_in,
                              void* d_out, int out_size, void* d_ws, size_t ws_size,
                              hipStream_t stream) {
    const float* embs      = (const float*)d_in[0];
    const int*   mask      = (const int*)d_in[1];
    const float* mlp_ln_g  = (const float*)d_in[2];
    const float* mlp_ln_b  = (const float*)d_in[3];
    const float* mlp_w1    = (const float*)d_in[4];
    const float* mlp_b1    = (const float*)d_in[5];
    const float* mlp_w2    = (const float*)d_in[6];
    const float* mlp_b2    = (const float*)d_in[7];
    const float* proj_in_w = (const float*)d_in[8];
    const float* proj_in_b = (const float*)d_in[9];
    const float* codebook  = (const float*)d_in[10];
    const float* proj_out_w= (const float*)d_in[11];
    const float* proj_out_b= (const float*)d_in[12];
    const float* pos_emb   = (const float*)d_in[13];
    const float* attn_ln_g = (const float*)d_in[14];
    const float* attn_ln_b = (const float*)d_in[15];
    const float* wq = (const float*)d_in[16];
    const float* bq = (const float*)d_in[17];
    const float* wk = (const float*)d_in[18];
    const float* bk = (const float*)d_in[19];
    const float* wv = (const float*)d_in[20];
    const float* bv = (const float*)d_in[21];
    const float* wo = (const float*)d_in[22];
    const float* bo = (const float*)d_in[23];
    const float* ffn_ln_g = (const float*)d_in[24];
    const float* ffn_ln_b = (const float*)d_in[25];
    const float* ffn_w1   = (const float*)d_in[26];
    const float* ffn_b1   = (const float*)d_in[27];
    const float* ffn_w2   = (const float*)d_in[28];
    const float* ffn_b2   = (const float*)d_in[29];
    const float* ln_post_g= (const float*)d_in[30];
    const float* ln_post_b= (const float*)d_in[31];

    float* ws = (float*)d_ws;
    float* ff1    = ws + OFF_FF1;    // MLP phase
    float* x0     = ws + OFF_X0;
    float* h0     = ws + OFF_H0;     // h0, then x1
    float* sc     = ws + OFF_SC;     // scores (attn) / ffc (FFN)
    float* xq     = ws + OFF_XQ;
    float* cbp    = ws + OFF_CBP;
    int*   idx    = (int*)(ws + OFF_IDX);
    float* commit = ws + OFF_COMMIT;
    float* x2     = ws + OFF_X2;     // x2, later x4
    float* h2     = ws + OFF_H2;     // h2, later o
    float* q      = ws + OFF_Q;      // q, later x3
    float* k      = ws + OFF_K;      // k, later h3
    float* v      = ws + OFF_V;
    float* out    = (float*)d_out;

    hipMemsetAsync(commit, 0, sizeof(float), stream);

    // downsample + LN
    k_ds_ln<<<N1, 128, 0, stream>>>(embs, mlp_ln_g, mlp_ln_b, x0, h0);
    // MLP1: gelu(h0 @ w1 + b1) -> ff1
    k_gemm<false, 1><<<dim3(47, 16, 1), 256, 0, stream>>>(
        h0, 512, 0, mlp_w1, 2048, 0, mlp_b1, nullptr, 0, ff1, 2048, 0, N1, 2048, 512);
    // MLP2: ff1 @ w2 + b2 + x0 -> x1 (in h0 slot)
    k_gemm<false, 2><<<dim3(47, 4, 1), 256, 0, stream>>>(
        ff1, 2048, 0, mlp_w2, 512, 0, mlp_b2, x0, 512, h0, 512, 0, N1, 512, 2048);
    // proj_in: x1 @ proj_in_w + b -> xq
    k_gemm<false, 0><<<dim3(47, 1, 1), 256, 0, stream>>>(
        h0, 512, 0, proj_in_w, 64, 0, proj_in_b, nullptr, 0, xq, 64, 0, N1, 64, 512);
    // VQ
    k_vq<<<N1, 256, 0, stream>>>(xq, codebook, idx, commit);
    // codebook projection: codebook @ proj_out_w + b -> cbp
    k_gemm<false, 0><<<dim3(9, 4, 1), 256, 0, stream>>>(
        codebook, 64, 0, proj_out_w, 512, 0, proj_out_b, nullptr, 0, cbp, 512, 0, CBN, 512, 64);
    // select + repeat + mask + pos + LN
    k_sel_pos_ln<<<N2, 128, 0, stream>>>(cbp, idx, mask, pos_emb, attn_ln_g, attn_ln_b, x2, h2);
    // QKV
    k_gemm<false, 0><<<dim3(94, 4, 1), 256, 0, stream>>>(
        h2, 512, 0, wq, 512, 0, bq, nullptr, 0, q, 512, 0, N2, 512, 512);
    k_gemm<false, 0><<<dim3(94, 4, 1), 256, 0, stream>>>(
        h2, 512, 0, wk, 512, 0, bk, nullptr, 0, k, 512, 0, N2, 512, 512);
    k_gemm<false, 0><<<dim3(94, 4, 1), 256, 0, stream>>>(
        h2, 512, 0, wv, 512, 0, bv, nullptr, 0, v, 512, 0, N2, 512, 512);
    // attention, per batch (scores buffer = sc, 8*1500*1500 floats)
    float* o = h2;  // h2 dead after QKV
    for (int b_ = 0; b_ < BB; b_++) {
        const float* qb = q + (long)b_ * TT * DD;
        const float* kb = k + (long)b_ * TT * DD;
        const float* vb = v + (long)b_ * TT * DD;
        float* ob = o + (long)b_ * TT * DD;
        // scores[h] = Q_h @ K_h^T
        k_gemm<true, 0><<<dim3(12, 12, 8), 256, 0, stream>>>(
            qb, 512, 64, kb, 512, 64, nullptr, nullptr, 0, sc, 1500, 2250000L, 1500, 1500, 64);
        k_softmax<<<dim3(1500, 8, 1), 256, 0, stream>>>(sc);
        // O_h = P_h @ V_h
        k_gemm<false, 0><<<dim3(12, 1, 8), 256, 0, stream>>>(
            sc, 1500, 2250000L, vb, 512, 64, nullptr, nullptr, 0, ob, 512, 64, 1500, 64, 1500);
    }
    // WO + residual -> x3 (in q slot)
    float* x3 = q;
    k_gemm<false, 2><<<dim3(94, 4, 1), 256, 0, stream>>>(
        o, 512, 0, wo, 512, 0, bo, x2, 512, x3, 512, 0, N2, 512, 512);
    // FFN (2 row-chunks of 6000 so the 2048-wide intermediate fits in sc)
    float* h3 = k;  // k dead after attention
    k_ln<<<N2, 128, 0, stream>>>(x3, ffn_ln_g, ffn_ln_b, h3);
    float* x4 = x2; // x2 dead after WO-residual
    for (int c = 0; c < 2; c++) {
        long ro = (long)c * 6000;
        k_gemm<false, 1><<<dim3(47, 16, 1), 256, 0, stream>>>(
            h3 + ro * 512, 512, 0, ffn_w1, 2048, 0, ffn_b1, nullptr, 0, sc, 2048, 0, 6000, 2048, 512);
        k_gemm<false, 2><<<dim3(47, 4, 1), 256, 0, stream>>>(
            sc, 2048, 0, ffn_w2, 512, 0, ffn_b2, x3 + ro * 512, 512, x4 + ro * 512, 512, 0, 6000, 512, 2048);
    }
    // final LN + commit loss
    k_ln_out<<<N2, 128, 0, stream>>>(x4, ln_post_g, ln_post_b, out, commit);
}

// Round 11
// 2027.320 us; speedup vs baseline: 2.3709x; 2.3709x over previous
//
#include <hip/hip_runtime.h>
#include <math.h>

typedef unsigned short u16;
typedef __attribute__((ext_vector_type(8))) short bf16x8;
typedef __attribute__((ext_vector_type(4))) float f32x4;

#define BB 8
#define TT 1500
#define DD 512
#define TSS 750
#define CBN 1025

static constexpr int N1 = BB * TSS;   // 6000
static constexpr int N2 = BB * TT;    // 12000
static constexpr long OUT_LOSS = (long)N2 * DD;

// ---- workspace byte offsets (peak 172.4 MB; 200.3 MB proven safe) ----
static constexpr long B_FF1   = 0;          // f32 6000x2048 (MLP phase)
static constexpr long B_X0    = 49152000;   // f32 6000x512  (MLP phase)
static constexpr long B_H0    = 61440000;   // f32 6000x512  h0 then x1
static constexpr long B_SC    = 0;          // f32 scores, per-batch 8h x1500x1536 (attn)
static constexpr long B_FFBF  = 0;          // bf16 12032x2048 (FFN)
static constexpr long B_X4    = 49283072;   // f32 12000x512 (FFN out)
static constexpr long B_X2    = 76005376;   // f32 12000x512 residual
static constexpr long B_H2BF  = 100581376;  // bf16 12032x512 h2bf, then obf
static constexpr long B_QKV   = 112902144;  // bf16 12032x1536; later x3/h3bf
static constexpr long B_X3    = 112902144;  // f32 12000x512
static constexpr long B_H3BF  = 137478144;  // bf16 12032x512
static constexpr long B_VT    = 149864448;  // bf16 64x64x1536
static constexpr long B_XQ    = 162447360;  // f32 6000x64
static constexpr long B_CBP   = 163983360;  // f32 1025x512
static constexpr long B_IDX   = 166082560;  // int 6000
static constexpr long B_CMT   = 166106624;  // f32
static constexpr long B_BQKV  = 166106880;  // f32 1536
static constexpr long B_WQKVT = 166113024;  // bf16 1536x512
static constexpr long B_WOT   = 167685888;  // bf16 512x512
static constexpr long B_W1T   = 168210176;  // bf16 2048x512
static constexpr long B_W2T   = 170307328;  // bf16 512x2048  (end 172404480)

__device__ __forceinline__ float gelu_tanh(float x) {
    float t = tanhf(0.7978845608028654f * (x + 0.044715f * x * x * x));
    return 0.5f * x * (1.0f + t);
}
__device__ __forceinline__ u16 f2b(float f) {   // f32 -> bf16 RNE
    unsigned u = __float_as_uint(f);
    return (u16)((u + 0x7FFFu + ((u >> 16) & 1u)) >> 16);
}

// ---------- LayerNorm family (block=128, row of 512) ----------
__device__ __forceinline__ void row_reduce2_128(float& s, float& sq) {
    int tid = threadIdx.x, lane = tid & 63, wid = tid >> 6;
    for (int off = 32; off > 0; off >>= 1) { s += __shfl_down(s, off); sq += __shfl_down(sq, off); }
    __shared__ float ss[2], ssq[2];
    if (lane == 0) { ss[wid] = s; ssq[wid] = sq; }
    __syncthreads();
    s = ss[0] + ss[1]; sq = ssq[0] + ssq[1];
}

__global__ __launch_bounds__(128) void k_ds_ln(const float* __restrict__ embs,
                                               const float* __restrict__ g, const float* __restrict__ be,
                                               float* __restrict__ x0, float* __restrict__ h0) {
    int r = blockIdx.x, b = r / TSS, ts = r - b * TSS;
    const float* src = embs + ((long)(b * TT + 2 * ts)) * DD;
    int tid = threadIdx.x;
    float4 v = *(const float4*)(src + tid * 4);
    float s = v.x + v.y + v.z + v.w, sq = v.x*v.x + v.y*v.y + v.z*v.z + v.w*v.w;
    row_reduce2_128(s, sq);
    float mean = s * (1.0f/DD), var = sq * (1.0f/DD) - mean*mean, rstd = rsqrtf(var + 1e-5f);
    float4 gv = *(const float4*)(g + tid * 4), bv = *(const float4*)(be + tid * 4);
    *(float4*)(x0 + (long)r * DD + tid * 4) = v;
    float4 hv = { (v.x-mean)*rstd*gv.x+bv.x, (v.y-mean)*rstd*gv.y+bv.y,
                  (v.z-mean)*rstd*gv.z+bv.z, (v.w-mean)*rstd*gv.w+bv.w };
    *(float4*)(h0 + (long)r * DD + tid * 4) = hv;
}

__global__ __launch_bounds__(128) void k_sel_pos_ln(const float* __restrict__ cbp,
                                                    const int* __restrict__ idxp, const int* __restrict__ mask,
                                                    const float* __restrict__ pos,
                                                    const float* __restrict__ g, const float* __restrict__ be,
                                                    float* __restrict__ x2, u16* __restrict__ h2bf) {
    int r = blockIdx.x, b = r / TT, t = r - b * TT;
    int code = mask[r] ? idxp[b * TSS + (t >> 1)] : (CBN - 1);
    int tid = threadIdx.x;
    float4 cv = *(const float4*)(cbp + (long)code * DD + tid * 4);
    float4 pv = *(const float4*)(pos + (long)t * DD + tid * 4);
    float4 v = { cv.x+pv.x, cv.y+pv.y, cv.z+pv.z, cv.w+pv.w };
    float s = v.x + v.y + v.z + v.w, sq = v.x*v.x + v.y*v.y + v.z*v.z + v.w*v.w;
    row_reduce2_128(s, sq);
    float mean = s * (1.0f/DD), var = sq * (1.0f/DD) - mean*mean, rstd = rsqrtf(var + 1e-5f);
    float4 gv = *(const float4*)(g + tid * 4), bv = *(const float4*)(be + tid * 4);
    *(float4*)(x2 + (long)r * DD + tid * 4) = v;
    float h0v = (v.x-mean)*rstd*gv.x+bv.x, h1v = (v.y-mean)*rstd*gv.y+bv.y;
    float h2v = (v.z-mean)*rstd*gv.z+bv.z, h3v = (v.w-mean)*rstd*gv.w+bv.w;
    u16 hb[4] = { f2b(h0v), f2b(h1v), f2b(h2v), f2b(h3v) };
    *(uint2*)(h2bf + (long)r * DD + tid * 4) = *(uint2*)hb;
}

__global__ __launch_bounds__(128) void k_ln_tobf(const float* __restrict__ xin,
                                                 const float* __restrict__ g, const float* __restrict__ be,
                                                 u16* __restrict__ hout) {
    int r = blockIdx.x, tid = threadIdx.x;
    float4 v = *(const float4*)(xin + (long)r * DD + tid * 4);
    float s = v.x + v.y + v.z + v.w, sq = v.x*v.x + v.y*v.y + v.z*v.z + v.w*v.w;
    row_reduce2_128(s, sq);
    float mean = s * (1.0f/DD), var = sq * (1.0f/DD) - mean*mean, rstd = rsqrtf(var + 1e-5f);
    float4 gv = *(const float4*)(g + tid * 4), bv = *(const float4*)(be + tid * 4);
    u16 hb[4] = { f2b((v.x-mean)*rstd*gv.x+bv.x), f2b((v.y-mean)*rstd*gv.y+bv.y),
                  f2b((v.z-mean)*rstd*gv.z+bv.z), f2b((v.w-mean)*rstd*gv.w+bv.w) };
    *(uint2*)(hout + (long)r * DD + tid * 4) = *(uint2*)hb;
}

__global__ __launch_bounds__(128) void k_ln_out(const float* __restrict__ xin,
                                                const float* __restrict__ g, const float* __restrict__ be,
                                                float* __restrict__ out, const float* __restrict__ commit) {
    int r = blockIdx.x, tid = threadIdx.x;
    float4 v = *(const float4*)(xin + (long)r * DD + tid * 4);
    float s = v.x + v.y + v.z + v.w, sq = v.x*v.x + v.y*v.y + v.z*v.z + v.w*v.w;
    row_reduce2_128(s, sq);
    float mean = s * (1.0f/DD), var = sq * (1.0f/DD) - mean*mean, rstd = rsqrtf(var + 1e-5f);
    float4 gv = *(const float4*)(g + tid * 4), bv = *(const float4*)(be + tid * 4);
    float4 hv = { (v.x-mean)*rstd*gv.x+bv.x, (v.y-mean)*rstd*gv.y+bv.y,
                  (v.z-mean)*rstd*gv.z+bv.z, (v.w-mean)*rstd*gv.w+bv.w };
    *(float4*)(out + (long)r * DD + tid * 4) = hv;
    if (r == 0 && tid == 0) out[OUT_LOSS] = commit[0] * (1.0f / 384000.0f);
}

// ---------- f32 tiled GEMM (pre-VQ path only; numerically locked) ----------
template <int EPI>   // 0 bias, 1 gelu+bias, 2 bias+res
__global__ __launch_bounds__(256) void k_gemm(const float* __restrict__ A, int lda,
                                              const float* __restrict__ Bm, int ldb,
                                              const float* __restrict__ bias,
                                              const float* __restrict__ Res, int ldr,
                                              float* __restrict__ C, int ldc,
                                              int M, int N, int K) {
    const int bm = blockIdx.x * 128, bn = blockIdx.y * 128;
    const int tid = threadIdx.x, tx = tid & 15, ty = tid >> 4;
    __shared__ float Ast[16][128], Bs[16][128];
    float acc[8][8];
#pragma unroll
    for (int i = 0; i < 8; i++)
#pragma unroll
        for (int j = 0; j < 8; j++) acc[i][j] = 0.f;
    const int am = tid >> 1, ak = (tid & 1) * 8;
    for (int k0 = 0; k0 < K; k0 += 16) {
        {
            int row = bm + am; float av[8];
            if (row < M && (k0 + ak + 7) < K) {
                float4 p0 = *(const float4*)(A + (long)row*lda + k0 + ak);
                float4 p1 = *(const float4*)(A + (long)row*lda + k0 + ak + 4);
                av[0]=p0.x;av[1]=p0.y;av[2]=p0.z;av[3]=p0.w;av[4]=p1.x;av[5]=p1.y;av[6]=p1.z;av[7]=p1.w;
            } else {
#pragma unroll
                for (int i = 0; i < 8; i++) { int kk = k0+ak+i; av[i] = (row<M && kk<K) ? A[(long)row*lda+kk] : 0.f; }
            }
#pragma unroll
            for (int i = 0; i < 8; i++) Ast[ak+i][am] = av[i];
        }
        {
            int krow = tid >> 4, n8 = (tid & 15) * 8, kk = k0 + krow, nn = bn + n8;
            float bvv[8];
            if (kk < K && (nn + 7) < N) {
                float4 p0 = *(const float4*)(Bm + (long)kk*ldb + nn);
                float4 p1 = *(const float4*)(Bm + (long)kk*ldb + nn + 4);
                bvv[0]=p0.x;bvv[1]=p0.y;bvv[2]=p0.z;bvv[3]=p0.w;bvv[4]=p1.x;bvv[5]=p1.y;bvv[6]=p1.z;bvv[7]=p1.w;
            } else {
#pragma unroll
                for (int i = 0; i < 8; i++) bvv[i] = (kk<K && (nn+i)<N) ? Bm[(long)kk*ldb+nn+i] : 0.f;
            }
#pragma unroll
            for (int i = 0; i < 8; i++) Bs[krow][n8+i] = bvv[i];
        }
        __syncthreads();
#pragma unroll
        for (int k = 0; k < 16; k++) {
            float a[8], bb[8];
            float4 t0 = *(const float4*)&Ast[k][ty*8], t1 = *(const float4*)&Ast[k][ty*8+4];
            a[0]=t0.x;a[1]=t0.y;a[2]=t0.z;a[3]=t0.w;a[4]=t1.x;a[5]=t1.y;a[6]=t1.z;a[7]=t1.w;
            float4 u0 = *(const float4*)&Bs[k][tx*8], u1 = *(const float4*)&Bs[k][tx*8+4];
            bb[0]=u0.x;bb[1]=u0.y;bb[2]=u0.z;bb[3]=u0.w;bb[4]=u1.x;bb[5]=u1.y;bb[6]=u1.z;bb[7]=u1.w;
#pragma unroll
            for (int i = 0; i < 8; i++)
#pragma unroll
                for (int j = 0; j < 8; j++) acc[i][j] = fmaf(a[i], bb[j], acc[i][j]);
        }
        __syncthreads();
    }
#pragma unroll
    for (int i = 0; i < 8; i++) {
        int m = bm + ty*8 + i; if (m >= M) continue;
#pragma unroll
        for (int j = 0; j < 8; j++) {
            int n = bn + tx*8 + j; if (n >= N) continue;
            float val = acc[i][j];
            if (bias) val += bias[n];
            if (EPI == 1) val = gelu_tanh(val);
            if (EPI == 2) val += Res[(long)m*ldr + n];
            C[(long)m*ldc + n] = val;
        }
    }
}

// ---------- bf16 MFMA GEMM: C = epi(A[M,K] @ Bt[N,K]^T + bias, Res) ----------
// A, Bt bf16; 128x128 tile, 4 waves, K-step 32; slot-swizzled LDS.
template <int EPI, bool OBF>   // EPI: 0 bias, 1 gelu+bias, 2 bias+res
__global__ __launch_bounds__(256) void k_bgemm(const u16* __restrict__ A, int lda, long sAi,
                                               const u16* __restrict__ Bt, int ldb, long sBi,
                                               const float* __restrict__ bias,
                                               const float* __restrict__ Res, int ldr,
                                               void* __restrict__ Cv, int ldc, long sCi,
                                               int M, int N, int K) {
    const int z = blockIdx.z;
    A  += (long)z * sAi;
    Bt += (long)z * sBi;
    const long cz = (long)z * sCi;
    const int bm = blockIdx.x * 128, bn = blockIdx.y * 128;
    const int tid = threadIdx.x, l = tid & 63, w = tid >> 6;
    const int wr = w >> 1, wc = w & 1;
    const bool wact = (bn + wc * 64) < N;

    __shared__ u16 sA[128 * 32], sB[128 * 32];
    f32x4 acc[4][4];
#pragma unroll
    for (int i = 0; i < 4; i++)
#pragma unroll
        for (int j = 0; j < 4; j++) acc[i][j] = (f32x4){0.f, 0.f, 0.f, 0.f};

    const u16* Ab = A + (long)bm * lda;
    const u16* Bb = Bt + (long)bn * ldb;
    const int e0 = tid, e1 = 256 + tid;

    auto LD = [&](const u16* base, int ld, int k0, int e) -> uint4 {
        int row = e >> 2, sl = e & 3;
        return *(const uint4*)(base + (long)row * ld + k0 + sl * 8);
    };
    auto ST = [&](u16* s, int e, uint4 v) {
        int row = e >> 2, sl = e & 3;
        int ph = (sl + ((row >> 1) & 3)) & 3;
        *(uint4*)&s[row * 32 + ph * 8] = v;
    };

    uint4 ra0 = LD(Ab, lda, 0, e0), ra1 = LD(Ab, lda, 0, e1);
    uint4 rb0 = LD(Bb, ldb, 0, e0), rb1 = LD(Bb, ldb, 0, e1);

    for (int k0 = 0; k0 < K; k0 += 32) {
        __syncthreads();           // previous tile's reads complete
        ST(sA, e0, ra0); ST(sA, e1, ra1);
        ST(sB, e0, rb0); ST(sB, e1, rb1);
        __syncthreads();
        int kn = k0 + 32;
        if (kn < K) {              // prefetch next tile; latency hides under MFMA
            ra0 = LD(Ab, lda, kn, e0); ra1 = LD(Ab, lda, kn, e1);
            rb0 = LD(Bb, ldb, kn, e0); rb1 = LD(Bb, ldb, kn, e1);
        }
        if (wact) {
            bf16x8 af[4], bfr[4];
#pragma unroll
            for (int f = 0; f < 4; f++) {
                int r = wr * 64 + f * 16 + (l & 15);
                int ph = ((l >> 4) + ((r >> 1) & 3)) & 3;
                af[f] = *(const bf16x8*)&sA[r * 32 + ph * 8];
                int n = wc * 64 + f * 16 + (l & 15);
                int ph2 = ((l >> 4) + ((n >> 1) & 3)) & 3;
                bfr[f] = *(const bf16x8*)&sB[n * 32 + ph2 * 8];
            }
#pragma unroll
            for (int i = 0; i < 4; i++)
#pragma unroll
                for (int j = 0; j < 4; j++)
                    acc[i][j] = __builtin_amdgcn_mfma_f32_16x16x32_bf16(af[i], bfr[j], acc[i][j], 0, 0, 0);
        }
    }
    if (!wact) return;
#pragma unroll
    for (int i = 0; i < 4; i++) {
#pragma unroll
        for (int j = 0; j < 4; j++) {
            int ncol = bn + wc * 64 + j * 16 + (l & 15);
            if (ncol >= N) continue;
            float badd = bias ? bias[ncol] : 0.0f;
#pragma unroll
            for (int ii = 0; ii < 4; ii++) {
                int m = bm + wr * 64 + i * 16 + (l >> 4) * 4 + ii;
                if (m >= M) continue;
                float val = acc[i][j][ii] + badd;
                if (EPI == 1) val = gelu_tanh(val);
                if (EPI == 2) val += Res[(long)m * ldr + ncol];
                if (OBF) ((u16*)Cv)[cz + (long)m * ldc + ncol] = f2b(val);
                else     ((float*)Cv)[cz + (long)m * ldc + ncol] = val;
            }
        }
    }
}

// ---------- weight convert+transpose: f32 [K][N] -> bf16 [N][K] ----------
__global__ __launch_bounds__(256) void k_wt(const float* __restrict__ src, u16* __restrict__ dst,
                                            int K, int N) {
    __shared__ float lds[64][68];
    int k0 = blockIdx.x * 64, n0 = blockIdx.y * 64, tid = threadIdx.x;
#pragma unroll
    for (int it = 0; it < 4; it++) {
        int c = it * 256 + tid, kr = c >> 4, nq = c & 15;
        float4 v = *(const float4*)(src + (long)(k0 + kr) * N + n0 + nq * 4);
        lds[nq*4+0][kr] = v.x; lds[nq*4+1][kr] = v.y; lds[nq*4+2][kr] = v.z; lds[nq*4+3][kr] = v.w;
    }
    __syncthreads();
#pragma unroll
    for (int it = 0; it < 4; it++) {
        int c = it * 256 + tid, n = c >> 4, kq = c & 15;
        float4 v = *(const float4*)&lds[n][kq * 4];
        u16 o[4] = { f2b(v.x), f2b(v.y), f2b(v.z), f2b(v.w) };
        *(uint2*)(dst + (long)(n0 + n) * K + k0 + kq * 4) = *(uint2*)o;
    }
}

__global__ __launch_bounds__(256) void k_bcat(const float* a, const float* b, const float* c,
                                              float* dst) {
    int i = blockIdx.x * 256 + threadIdx.x;
    if (i < 512) dst[i] = a[i];
    else if (i < 1024) dst[i] = b[i - 512];
    else if (i < 1536) dst[i] = c[i - 1024];
}

// ---------- V transpose: qkv v-cols -> Vt[bh][64][1536] ----------
__global__ __launch_bounds__(256) void k_vtrans(const u16* __restrict__ qkv, u16* __restrict__ Vt) {
    __shared__ u16 lds[64][72];
    int gh = blockIdx.y, b = gh >> 3, h = gh & 7;
    int t0 = blockIdx.x * 64, tid = threadIdx.x;
#pragma unroll
    for (int it = 0; it < 2; it++) {
        int c = it * 256 + tid, tok = c >> 3, dq = c & 7;
        uint4 v = *(const uint4*)(qkv + (long)(b * TT + t0 + tok) * 1536 + 1024 + h * 64 + dq * 8);
        u16 s[8]; *(uint4*)s = v;
#pragma unroll
        for (int j = 0; j < 8; j++) lds[dq * 8 + j][tok] = s[j];
    }
    __syncthreads();
#pragma unroll
    for (int it = 0; it < 2; it++) {
        int c = it * 256 + tid, d = c >> 3, tq = c & 7;
        uint4 v = *(const uint4*)&lds[d][tq * 8];
        *(uint4*)(Vt + (long)gh * 98304 + (long)d * 1536 + t0 + tq * 8) = v;
    }
}

// ---------- VQ argmin (f64) + commit ----------
__global__ __launch_bounds__(256) void k_vq(const float* __restrict__ xq, const float* __restrict__ cb,
                                            int* __restrict__ idx, float* __restrict__ commit) {
    __shared__ float xs[64];
    __shared__ double sd[256];
    __shared__ int si[256];
    int r = blockIdx.x, tid = threadIdx.x;
    if (tid < 64) xs[tid] = xq[(long)r * 64 + tid];
    __syncthreads();
    double bestd = 1e300; int bi = 0;
    for (int c = tid; c < CBN; c += 256) {
        const float* crow = cb + (long)c * 64;
        double sacc = 0.0;
#pragma unroll 8
        for (int d = 0; d < 64; d++) { float diff = xs[d] - crow[d]; sacc = fma((double)diff, (double)diff, sacc); }
        if (sacc < bestd) { bestd = sacc; bi = c; }
    }
    sd[tid] = bestd; si[tid] = bi;
    __syncthreads();
    for (int off = 128; off > 0; off >>= 1) {
        if (tid < off) {
            if (sd[tid+off] < sd[tid] || (sd[tid+off] == sd[tid] && si[tid+off] < si[tid])) {
                sd[tid] = sd[tid+off]; si[tid] = si[tid+off];
            }
        }
        __syncthreads();
    }
    int win = si[0];
    if (tid == 0) idx[r] = win;
    if (tid < 64) {
        float diff = cb[(long)win * 64 + tid] - xs[tid];
        float sq = diff * diff;
        for (int off = 32; off > 0; off >>= 1) sq += __shfl_down(sq, off);
        if (tid == 0) atomicAdd(commit, sq);
    }
}

// ---------- softmax over 1500, f32 in -> bf16 out IN-PLACE (row-local) ----------
__global__ __launch_bounds__(256) void k_softmax_bf(float* __restrict__ sc) {
    float* row = sc + (long)blockIdx.y * 2304000 + (long)blockIdx.x * 1536;
    u16* prow = (u16*)row;                       // bf16 row over first half of f32 row
    int tid = threadIdx.x, lane = tid & 63, wid = tid >> 6;
    float v[6], mx = -1e30f;
#pragma unroll
    for (int l = 0; l < 6; l++) { int j = tid + l * 256; v[l] = (j < 1500) ? row[j] : -1e30f; mx = fmaxf(mx, v[l]); }
    for (int off = 32; off > 0; off >>= 1) mx = fmaxf(mx, __shfl_down(mx, off));
    __shared__ float sm[4];
    if (!lane) sm[wid] = mx;
    __syncthreads();
    mx = fmaxf(fmaxf(sm[0], sm[1]), fmaxf(sm[2], sm[3]));
    float s = 0.f;
#pragma unroll
    for (int l = 0; l < 6; l++) { int j = tid + l * 256; float e = (j < 1500) ? expf(v[l] - mx) : 0.f; v[l] = e; s += e; }
    for (int off = 32; off > 0; off >>= 1) s += __shfl_down(s, off);
    __shared__ float ssum[4];
    if (!lane) ssum[wid] = s;
    __syncthreads();
    s = ssum[0] + ssum[1] + ssum[2] + ssum[3];
    float inv = 1.0f / s;
#pragma unroll
    for (int l = 0; l < 6; l++) { int j = tid + l * 256; prow[j] = (j < 1500) ? f2b(v[l] * inv) : (u16)0; }
}

extern "C" void kernel_launch(void* const* d_in, const int* in_sizes, int n_in,
                              void* d_out, int out_size, void* d_ws, size_t ws_size,
                              hipStream_t stream) {
    const float* embs      = (const float*)d_in[0];
    const int*   mask      = (const int*)d_in[1];
    const float* mlp_ln_g  = (const float*)d_in[2];
    const float* mlp_ln_b  = (const float*)d_in[3];
    const float* mlp_w1    = (const float*)d_in[4];
    const float* mlp_b1    = (const float*)d_in[5];
    const float* mlp_w2    = (const float*)d_in[6];
    const float* mlp_b2    = (const float*)d_in[7];
    const float* proj_in_w = (const float*)d_in[8];
    const float* proj_in_b = (const float*)d_in[9];
    const float* codebook  = (const float*)d_in[10];
    const float* proj_out_w= (const float*)d_in[11];
    const float* proj_out_b= (const float*)d_in[12];
    const float* pos_emb   = (const float*)d_in[13];
    const float* attn_ln_g = (const float*)d_in[14];
    const float* attn_ln_b = (const float*)d_in[15];
    const float* wq = (const float*)d_in[16];
    const float* bq = (const float*)d_in[17];
    const float* wk = (const float*)d_in[18];
    const float* bk = (const float*)d_in[19];
    const float* wv = (const float*)d_in[20];
    const float* bv = (const float*)d_in[21];
    const float* wo = (const float*)d_in[22];
    const float* bo = (const float*)d_in[23];
    const float* ffn_ln_g = (const float*)d_in[24];
    const float* ffn_ln_b = (const float*)d_in[25];
    const float* ffn_w1   = (const float*)d_in[26];
    const float* ffn_b1   = (const float*)d_in[27];
    const float* ffn_w2   = (const float*)d_in[28];
    const float* ffn_b2   = (const float*)d_in[29];
    const float* ln_post_g= (const float*)d_in[30];
    const float* ln_post_b= (const float*)d_in[31];

    char* wsb = (char*)d_ws;
    float* ff1   = (float*)(wsb + B_FF1);
    float* x0    = (float*)(wsb + B_X0);
    float* h0    = (float*)(wsb + B_H0);     // h0 then x1
    float* sc    = (float*)(wsb + B_SC);
    u16*   ffbf  = (u16*)(wsb + B_FFBF);
    float* x4    = (float*)(wsb + B_X4);
    float* x2    = (float*)(wsb + B_X2);
    u16*   h2bf  = (u16*)(wsb + B_H2BF);     // then obf
    u16*   obf   = (u16*)(wsb + B_H2BF);
    u16*   qkv   = (u16*)(wsb + B_QKV);
    float* x3    = (float*)(wsb + B_X3);
    u16*   h3bf  = (u16*)(wsb + B_H3BF);
    u16*   Vt    = (u16*)(wsb + B_VT);
    float* xq    = (float*)(wsb + B_XQ);
    float* cbp   = (float*)(wsb + B_CBP);
    int*   idx   = (int*)(wsb + B_IDX);
    float* commit= (float*)(wsb + B_CMT);
    float* bqkv  = (float*)(wsb + B_BQKV);
    u16*   wqkvt = (u16*)(wsb + B_WQKVT);
    u16*   wot   = (u16*)(wsb + B_WOT);
    u16*   w1t   = (u16*)(wsb + B_W1T);
    u16*   w2t   = (u16*)(wsb + B_W2T);
    float* out   = (float*)d_out;

    hipMemsetAsync(commit, 0, sizeof(float), stream);

    // weight conversions (bf16, transposed to [N][K]) + bias concat
    k_wt<<<dim3(8, 8), 256, 0, stream>>>(wq, wqkvt,               512, 512);
    k_wt<<<dim3(8, 8), 256, 0, stream>>>(wk, wqkvt + 512 * 512,   512, 512);
    k_wt<<<dim3(8, 8), 256, 0, stream>>>(wv, wqkvt + 1024 * 512,  512, 512);
    k_wt<<<dim3(8, 8), 256, 0, stream>>>(wo, wot,                 512, 512);
    k_wt<<<dim3(8, 32), 256, 0, stream>>>(ffn_w1, w1t,            512, 2048);
    k_wt<<<dim3(32, 8), 256, 0, stream>>>(ffn_w2, w2t,            2048, 512);
    k_bcat<<<6, 256, 0, stream>>>(bq, bk, bv, bqkv);

    // ---- pre-VQ path (f32, numerically locked for argmin stability) ----
    k_ds_ln<<<N1, 128, 0, stream>>>(embs, mlp_ln_g, mlp_ln_b, x0, h0);
    k_gemm<1><<<dim3(47, 16), 256, 0, stream>>>(h0, 512, mlp_w1, 2048, mlp_b1, nullptr, 0, ff1, 2048, N1, 2048, 512);
    k_gemm<2><<<dim3(47, 4), 256, 0, stream>>>(ff1, 2048, mlp_w2, 512, mlp_b2, x0, 512, h0, 512, N1, 512, 2048);
    k_gemm<0><<<dim3(47, 1), 256, 0, stream>>>(h0, 512, proj_in_w, 64, proj_in_b, nullptr, 0, xq, 64, N1, 64, 512);
    k_vq<<<N1, 256, 0, stream>>>(xq, codebook, idx, commit);
    k_gemm<0><<<dim3(9, 4), 256, 0, stream>>>(codebook, 64, proj_out_w, 512, proj_out_b, nullptr, 0, cbp, 512, CBN, 512, 64);
    k_sel_pos_ln<<<N2, 128, 0, stream>>>(cbp, idx, mask, pos_emb, attn_ln_g, attn_ln_b, x2, h2bf);

    // ---- transformer block (bf16 MFMA) ----
    // QKV fused: [12000,1536] = h2bf @ [wq|wk|wv]
    k_bgemm<0, true><<<dim3(94, 12, 1), 256, 0, stream>>>(
        h2bf, 512, 0, wqkvt, 512, 0, bqkv, nullptr, 0, qkv, 1536, 0, N2, 1536, 512);
    k_vtrans<<<dim3(24, 64), 256, 0, stream>>>(qkv, Vt);

    for (int b = 0; b < BB; b++) {
        const u16* qb = qkv + (long)b * TT * 1536;
        // scores[h] = Q_h @ K_h^T   (f32 out, ldc 1536, K=64)
        k_bgemm<0, false><<<dim3(12, 12, 8), 256, 0, stream>>>(
            qb, 1536, 64, qb + 512, 1536, 64, nullptr, nullptr, 0,
            sc, 1536, 2304000L, TT, TT, 64);
        k_softmax_bf<<<dim3(TT, 8), 256, 0, stream>>>(sc);
        // O_h = P_h @ V_h^T  (P bf16 in-place over scores, lda 3072 shorts)
        k_bgemm<0, true><<<dim3(12, 1, 8), 256, 0, stream>>>(
            (const u16*)sc, 3072, 4608000L, Vt + (long)b * 8 * 98304, 1536, 98304L, nullptr, nullptr, 0,
            obf + (long)b * TT * 512, 512, 64L, TT, 64, 1536);
    }

    // WO + residual -> x3 (overwrites qkv slot; qkv dead)
    k_bgemm<2, false><<<dim3(94, 4, 1), 256, 0, stream>>>(
        obf, 512, 0, wot, 512, 0, bo, x2, 512, x3, 512, 0, N2, 512, 512);
    // FFN
    k_ln_tobf<<<N2, 128, 0, stream>>>(x3, ffn_ln_g, ffn_ln_b, h3bf);
    k_bgemm<1, true><<<dim3(94, 16, 1), 256, 0, stream>>>(
        h3bf, 512, 0, w1t, 512, 0, ffn_b1, nullptr, 0, ffbf, 2048, 0, N2, 2048, 512);
    k_bgemm<2, false><<<dim3(94, 4, 1), 256, 0, stream>>>(
        ffbf, 2048, 0, w2t, 2048, 0, ffn_b2, x3, 512, x4, 512, 0, N2, 512, 2048);
    // final LN + commit loss
    k_ln_out<<<N2, 128, 0, stream>>>(x4, ln_post_g, ln_post_b, out, commit);
}

// Round 12
// 1883.484 us; speedup vs baseline: 2.5519x; 1.0764x over previous
//
#include <hip/hip_runtime.h>
#include <math.h>

typedef unsigned short u16;
typedef __attribute__((ext_vector_type(8))) short bf16x8;
typedef __attribute__((ext_vector_type(4))) float f32x4;

#define BB 8
#define TT 1500
#define DD 512
#define TSS 750
#define CBN 1025

static constexpr int N1 = BB * TSS;   // 6000
static constexpr int N2 = BB * TT;    // 12000
static constexpr long OUT_LOSS = (long)N2 * DD;

// ---- workspace byte offsets (peak 172.4 MB; 200.3 MB proven safe) ----
static constexpr long B_FF1   = 0;          // f32 6000x2048 (MLP phase)
static constexpr long B_X0    = 49152000;   // f32 6000x512  (MLP phase)
static constexpr long B_H0    = 61440000;   // f32 6000x512  h0 then x1
static constexpr long B_SC    = 0;          // f32 scores, per-batch 8h x1500x1536 (attn)
static constexpr long B_FFBF  = 0;          // bf16 12032x2048 (FFN)
static constexpr long B_X4    = 49283072;   // f32 12000x512 (FFN out)
static constexpr long B_X2    = 76005376;   // f32 12000x512 residual
static constexpr long B_H2BF  = 100581376;  // bf16 12032x512 h2bf, then obf
static constexpr long B_QKV   = 112902144;  // bf16 12032x1536; later x3/h3bf
static constexpr long B_X3    = 112902144;  // f32 12000x512
static constexpr long B_H3BF  = 137478144;  // bf16 12032x512
static constexpr long B_VT    = 149864448;  // bf16 64x64x1536
static constexpr long B_XQ    = 162447360;  // f32 6000x64
static constexpr long B_CBP   = 163983360;  // f32 1025x512
static constexpr long B_IDX   = 166082560;  // int 6000
static constexpr long B_CMT   = 166106624;  // f32
static constexpr long B_BQKV  = 166106880;  // f32 1536
static constexpr long B_WQKVT = 166113024;  // bf16 1536x512
static constexpr long B_WOT   = 167685888;  // bf16 512x512
static constexpr long B_W1T   = 168210176;  // bf16 2048x512
static constexpr long B_W2T   = 170307328;  // bf16 512x2048  (end 172404480)

__device__ __forceinline__ float gelu_tanh(float x) {
    float t = tanhf(0.7978845608028654f * (x + 0.044715f * x * x * x));
    return 0.5f * x * (1.0f + t);
}
__device__ __forceinline__ u16 f2b(float f) {   // f32 -> bf16 RNE
    unsigned u = __float_as_uint(f);
    return (u16)((u + 0x7FFFu + ((u >> 16) & 1u)) >> 16);
}

// ---------- LayerNorm family (block=128, row of 512) ----------
__device__ __forceinline__ void row_reduce2_128(float& s, float& sq) {
    int tid = threadIdx.x, lane = tid & 63, wid = tid >> 6;
    for (int off = 32; off > 0; off >>= 1) { s += __shfl_down(s, off); sq += __shfl_down(sq, off); }
    __shared__ float ss[2], ssq[2];
    if (lane == 0) { ss[wid] = s; ssq[wid] = sq; }
    __syncthreads();
    s = ss[0] + ss[1]; sq = ssq[0] + ssq[1];
}

__global__ __launch_bounds__(128) void k_ds_ln(const float* __restrict__ embs,
                                               const float* __restrict__ g, const float* __restrict__ be,
                                               float* __restrict__ x0, float* __restrict__ h0) {
    int r = blockIdx.x, b = r / TSS, ts = r - b * TSS;
    const float* src = embs + ((long)(b * TT + 2 * ts)) * DD;
    int tid = threadIdx.x;
    float4 v = *(const float4*)(src + tid * 4);
    float s = v.x + v.y + v.z + v.w, sq = v.x*v.x + v.y*v.y + v.z*v.z + v.w*v.w;
    row_reduce2_128(s, sq);
    float mean = s * (1.0f/DD), var = sq * (1.0f/DD) - mean*mean, rstd = rsqrtf(var + 1e-5f);
    float4 gv = *(const float4*)(g + tid * 4), bv = *(const float4*)(be + tid * 4);
    *(float4*)(x0 + (long)r * DD + tid * 4) = v;
    float4 hv = { (v.x-mean)*rstd*gv.x+bv.x, (v.y-mean)*rstd*gv.y+bv.y,
                  (v.z-mean)*rstd*gv.z+bv.z, (v.w-mean)*rstd*gv.w+bv.w };
    *(float4*)(h0 + (long)r * DD + tid * 4) = hv;
}

__global__ __launch_bounds__(128) void k_sel_pos_ln(const float* __restrict__ cbp,
                                                    const int* __restrict__ idxp, const int* __restrict__ mask,
                                                    const float* __restrict__ pos,
                                                    const float* __restrict__ g, const float* __restrict__ be,
                                                    float* __restrict__ x2, u16* __restrict__ h2bf) {
    int r = blockIdx.x, b = r / TT, t = r - b * TT;
    int code = mask[r] ? idxp[b * TSS + (t >> 1)] : (CBN - 1);
    int tid = threadIdx.x;
    float4 cv = *(const float4*)(cbp + (long)code * DD + tid * 4);
    float4 pv = *(const float4*)(pos + (long)t * DD + tid * 4);
    float4 v = { cv.x+pv.x, cv.y+pv.y, cv.z+pv.z, cv.w+pv.w };
    float s = v.x + v.y + v.z + v.w, sq = v.x*v.x + v.y*v.y + v.z*v.z + v.w*v.w;
    row_reduce2_128(s, sq);
    float mean = s * (1.0f/DD), var = sq * (1.0f/DD) - mean*mean, rstd = rsqrtf(var + 1e-5f);
    float4 gv = *(const float4*)(g + tid * 4), bv = *(const float4*)(be + tid * 4);
    *(float4*)(x2 + (long)r * DD + tid * 4) = v;
    float h0v = (v.x-mean)*rstd*gv.x+bv.x, h1v = (v.y-mean)*rstd*gv.y+bv.y;
    float h2v = (v.z-mean)*rstd*gv.z+bv.z, h3v = (v.w-mean)*rstd*gv.w+bv.w;
    u16 hb[4] = { f2b(h0v), f2b(h1v), f2b(h2v), f2b(h3v) };
    *(uint2*)(h2bf + (long)r * DD + tid * 4) = *(uint2*)hb;
}

__global__ __launch_bounds__(128) void k_ln_tobf(const float* __restrict__ xin,
                                                 const float* __restrict__ g, const float* __restrict__ be,
                                                 u16* __restrict__ hout) {
    int r = blockIdx.x, tid = threadIdx.x;
    float4 v = *(const float4*)(xin + (long)r * DD + tid * 4);
    float s = v.x + v.y + v.z + v.w, sq = v.x*v.x + v.y*v.y + v.z*v.z + v.w*v.w;
    row_reduce2_128(s, sq);
    float mean = s * (1.0f/DD), var = sq * (1.0f/DD) - mean*mean, rstd = rsqrtf(var + 1e-5f);
    float4 gv = *(const float4*)(g + tid * 4), bv = *(const float4*)(be + tid * 4);
    u16 hb[4] = { f2b((v.x-mean)*rstd*gv.x+bv.x), f2b((v.y-mean)*rstd*gv.y+bv.y),
                  f2b((v.z-mean)*rstd*gv.z+bv.z), f2b((v.w-mean)*rstd*gv.w+bv.w) };
    *(uint2*)(hout + (long)r * DD + tid * 4) = *(uint2*)hb;
}

__global__ __launch_bounds__(128) void k_ln_out(const float* __restrict__ xin,
                                                const float* __restrict__ g, const float* __restrict__ be,
                                                float* __restrict__ out, const float* __restrict__ commit) {
    int r = blockIdx.x, tid = threadIdx.x;
    float4 v = *(const float4*)(xin + (long)r * DD + tid * 4);
    float s = v.x + v.y + v.z + v.w, sq = v.x*v.x + v.y*v.y + v.z*v.z + v.w*v.w;
    row_reduce2_128(s, sq);
    float mean = s * (1.0f/DD), var = sq * (1.0f/DD) - mean*mean, rstd = rsqrtf(var + 1e-5f);
    float4 gv = *(const float4*)(g + tid * 4), bv = *(const float4*)(be + tid * 4);
    float4 hv = { (v.x-mean)*rstd*gv.x+bv.x, (v.y-mean)*rstd*gv.y+bv.y,
                  (v.z-mean)*rstd*gv.z+bv.z, (v.w-mean)*rstd*gv.w+bv.w };
    *(float4*)(out + (long)r * DD + tid * 4) = hv;
    if (r == 0 && tid == 0) out[OUT_LOSS] = commit[0] * (1.0f / 384000.0f);
}

// ---------- f32 tiled GEMM (pre-VQ path; numerically locked) ----------
// BM x 128 tile, 256 threads, per-thread (BM/16) x 8. Accumulation strictly
// k-sequential per output element => bit-identical results across BM choices.
template <int BM, int EPI>   // EPI: 0 bias, 1 gelu+bias, 2 bias+res
__global__ __launch_bounds__(256) void k_gemm(const float* __restrict__ A, int lda,
                                              const float* __restrict__ Bm, int ldb,
                                              const float* __restrict__ bias,
                                              const float* __restrict__ Res, int ldr,
                                              float* __restrict__ C, int ldc,
                                              int M, int N, int K) {
    constexpr int TM = BM / 16;          // 8 for BM=128, 4 for BM=64
    constexpr int AE = BM / 16;          // A floats per thread per k-step
    const int bm = blockIdx.x * BM, bn = blockIdx.y * 128;
    const int tid = threadIdx.x, tx = tid & 15, ty = tid >> 4;
    __shared__ float Ast[16][BM], Bs[16][128];
    float acc[TM][8];
#pragma unroll
    for (int i = 0; i < TM; i++)
#pragma unroll
        for (int j = 0; j < 8; j++) acc[i][j] = 0.f;
    const int am = tid / (256 / BM);           // row within tile
    const int ak = (tid % (256 / BM)) * AE;    // k offset
    for (int k0 = 0; k0 < K; k0 += 16) {
        {   // ---- A tile ----
            int row = bm + am; float av[AE];
            if (row < M && (k0 + ak + AE - 1) < K) {
                if (AE == 8) {
                    float4 p0 = *(const float4*)(A + (long)row*lda + k0 + ak);
                    float4 p1 = *(const float4*)(A + (long)row*lda + k0 + ak + 4);
                    av[0]=p0.x;av[1]=p0.y;av[2]=p0.z;av[3]=p0.w;
                    av[4]=p1.x;av[5]=p1.y;av[6]=p1.z;av[7]=p1.w;
                } else {
                    float4 p0 = *(const float4*)(A + (long)row*lda + k0 + ak);
                    av[0]=p0.x;av[1]=p0.y;av[2]=p0.z;av[3]=p0.w;
                }
            } else {
#pragma unroll
                for (int i = 0; i < AE; i++) { int kk = k0+ak+i; av[i] = (row<M && kk<K) ? A[(long)row*lda+kk] : 0.f; }
            }
#pragma unroll
            for (int i = 0; i < AE; i++) Ast[ak+i][am] = av[i];
        }
        {   // ---- B tile (16 x 128) ----
            int krow = tid >> 4, n8 = (tid & 15) * 8, kk = k0 + krow, nn = bn + n8;
            float bvv[8];
            if (kk < K && (nn + 7) < N) {
                float4 p0 = *(const float4*)(Bm + (long)kk*ldb + nn);
                float4 p1 = *(const float4*)(Bm + (long)kk*ldb + nn + 4);
                bvv[0]=p0.x;bvv[1]=p0.y;bvv[2]=p0.z;bvv[3]=p0.w;bvv[4]=p1.x;bvv[5]=p1.y;bvv[6]=p1.z;bvv[7]=p1.w;
            } else {
#pragma unroll
                for (int i = 0; i < 8; i++) bvv[i] = (kk<K && (nn+i)<N) ? Bm[(long)kk*ldb+nn+i] : 0.f;
            }
#pragma unroll
            for (int i = 0; i < 8; i++) Bs[krow][n8+i] = bvv[i];
        }
        __syncthreads();
#pragma unroll
        for (int k = 0; k < 16; k++) {
            float a[TM], bb[8];
            if (TM == 8) {
                float4 t0 = *(const float4*)&Ast[k][ty*8], t1 = *(const float4*)&Ast[k][ty*8+4];
                a[0]=t0.x;a[1]=t0.y;a[2]=t0.z;a[3]=t0.w;a[4]=t1.x;a[5]=t1.y;a[6]=t1.z;a[7]=t1.w;
            } else {
                float4 t0 = *(const float4*)&Ast[k][ty*4];
                a[0]=t0.x;a[1]=t0.y;a[2]=t0.z;a[3]=t0.w;
            }
            float4 u0 = *(const float4*)&Bs[k][tx*8], u1 = *(const float4*)&Bs[k][tx*8+4];
            bb[0]=u0.x;bb[1]=u0.y;bb[2]=u0.z;bb[3]=u0.w;bb[4]=u1.x;bb[5]=u1.y;bb[6]=u1.z;bb[7]=u1.w;
#pragma unroll
            for (int i = 0; i < TM; i++)
#pragma unroll
                for (int j = 0; j < 8; j++) acc[i][j] = fmaf(a[i], bb[j], acc[i][j]);
        }
        __syncthreads();
    }
#pragma unroll
    for (int i = 0; i < TM; i++) {
        int m = bm + ty*TM + i; if (m >= M) continue;
#pragma unroll
        for (int j = 0; j < 8; j++) {
            int n = bn + tx*8 + j; if (n >= N) continue;
            float val = acc[i][j];
            if (bias) val += bias[n];
            if (EPI == 1) val = gelu_tanh(val);
            if (EPI == 2) val += Res[(long)m*ldr + n];
            C[(long)m*ldc + n] = val;
        }
    }
}

// ---------- bf16 MFMA GEMM: C = epi(A[M,K] @ Bt[N,K]^T + bias, Res) ----------
// A, Bt bf16; 128x128 tile, 4 waves, K-step 32; slot-swizzled LDS.
template <int EPI, bool OBF>   // EPI: 0 bias, 1 gelu+bias, 2 bias+res
__global__ __launch_bounds__(256) void k_bgemm(const u16* __restrict__ A, int lda, long sAi,
                                               const u16* __restrict__ Bt, int ldb, long sBi,
                                               const float* __restrict__ bias,
                                               const float* __restrict__ Res, int ldr,
                                               void* __restrict__ Cv, int ldc, long sCi,
                                               int M, int N, int K) {
    const int z = blockIdx.z;
    A  += (long)z * sAi;
    Bt += (long)z * sBi;
    const long cz = (long)z * sCi;
    const int bm = blockIdx.x * 128, bn = blockIdx.y * 128;
    const int tid = threadIdx.x, l = tid & 63, w = tid >> 6;
    const int wr = w >> 1, wc = w & 1;
    const bool wact = (bn + wc * 64) < N;

    __shared__ u16 sA[128 * 32], sB[128 * 32];
    f32x4 acc[4][4];
#pragma unroll
    for (int i = 0; i < 4; i++)
#pragma unroll
        for (int j = 0; j < 4; j++) acc[i][j] = (f32x4){0.f, 0.f, 0.f, 0.f};

    const u16* Ab = A + (long)bm * lda;
    const u16* Bb = Bt + (long)bn * ldb;
    const int e0 = tid, e1 = 256 + tid;

    auto LD = [&](const u16* base, int ld, int k0, int e) -> uint4 {
        int row = e >> 2, sl = e & 3;
        return *(const uint4*)(base + (long)row * ld + k0 + sl * 8);
    };
    auto ST = [&](u16* s, int e, uint4 v) {
        int row = e >> 2, sl = e & 3;
        int ph = (sl + ((row >> 1) & 3)) & 3;
        *(uint4*)&s[row * 32 + ph * 8] = v;
    };

    uint4 ra0 = LD(Ab, lda, 0, e0), ra1 = LD(Ab, lda, 0, e1);
    uint4 rb0 = LD(Bb, ldb, 0, e0), rb1 = LD(Bb, ldb, 0, e1);

    for (int k0 = 0; k0 < K; k0 += 32) {
        __syncthreads();           // previous tile's reads complete
        ST(sA, e0, ra0); ST(sA, e1, ra1);
        ST(sB, e0, rb0); ST(sB, e1, rb1);
        __syncthreads();
        int kn = k0 + 32;
        if (kn < K) {              // prefetch next tile; latency hides under MFMA
            ra0 = LD(Ab, lda, kn, e0); ra1 = LD(Ab, lda, kn, e1);
            rb0 = LD(Bb, ldb, kn, e0); rb1 = LD(Bb, ldb, kn, e1);
        }
        if (wact) {
            bf16x8 af[4], bfr[4];
#pragma unroll
            for (int f = 0; f < 4; f++) {
                int r = wr * 64 + f * 16 + (l & 15);
                int ph = ((l >> 4) + ((r >> 1) & 3)) & 3;
                af[f] = *(const bf16x8*)&sA[r * 32 + ph * 8];
                int n = wc * 64 + f * 16 + (l & 15);
                int ph2 = ((l >> 4) + ((n >> 1) & 3)) & 3;
                bfr[f] = *(const bf16x8*)&sB[n * 32 + ph2 * 8];
            }
#pragma unroll
            for (int i = 0; i < 4; i++)
#pragma unroll
                for (int j = 0; j < 4; j++)
                    acc[i][j] = __builtin_amdgcn_mfma_f32_16x16x32_bf16(af[i], bfr[j], acc[i][j], 0, 0, 0);
        }
    }
    if (!wact) return;
#pragma unroll
    for (int i = 0; i < 4; i++) {
#pragma unroll
        for (int j = 0; j < 4; j++) {
            int ncol = bn + wc * 64 + j * 16 + (l & 15);
            if (ncol >= N) continue;
            float badd = bias ? bias[ncol] : 0.0f;
#pragma unroll
            for (int ii = 0; ii < 4; ii++) {
                int m = bm + wr * 64 + i * 16 + (l >> 4) * 4 + ii;
                if (m >= M) continue;
                float val = acc[i][j][ii] + badd;
                if (EPI == 1) val = gelu_tanh(val);
                if (EPI == 2) val += Res[(long)m * ldr + ncol];
                if (OBF) ((u16*)Cv)[cz + (long)m * ldc + ncol] = f2b(val);
                else     ((float*)Cv)[cz + (long)m * ldc + ncol] = val;
            }
        }
    }
}

// ---------- weight convert+transpose: f32 [K][N] -> bf16 [N][K] ----------
__global__ __launch_bounds__(256) void k_wt(const float* __restrict__ src, u16* __restrict__ dst,
                                            int K, int N) {
    __shared__ float lds[64][68];
    int k0 = blockIdx.x * 64, n0 = blockIdx.y * 64, tid = threadIdx.x;
#pragma unroll
    for (int it = 0; it < 4; it++) {
        int c = it * 256 + tid, kr = c >> 4, nq = c & 15;
        float4 v = *(const float4*)(src + (long)(k0 + kr) * N + n0 + nq * 4);
        lds[nq*4+0][kr] = v.x; lds[nq*4+1][kr] = v.y; lds[nq*4+2][kr] = v.z; lds[nq*4+3][kr] = v.w;
    }
    __syncthreads();
#pragma unroll
    for (int it = 0; it < 4; it++) {
        int c = it * 256 + tid, n = c >> 4, kq = c & 15;
        float4 v = *(const float4*)&lds[n][kq * 4];
        u16 o[4] = { f2b(v.x), f2b(v.y), f2b(v.z), f2b(v.w) };
        *(uint2*)(dst + (long)(n0 + n) * K + k0 + kq * 4) = *(uint2*)o;
    }
}

__global__ __launch_bounds__(256) void k_bcat(const float* a, const float* b, const float* c,
                                              float* dst) {
    int i = blockIdx.x * 256 + threadIdx.x;
    if (i < 512) dst[i] = a[i];
    else if (i < 1024) dst[i] = b[i - 512];
    else if (i < 1536) dst[i] = c[i - 1024];
}

// ---------- V transpose: qkv v-cols -> Vt[bh][64][1536] ----------
__global__ __launch_bounds__(256) void k_vtrans(const u16* __restrict__ qkv, u16* __restrict__ Vt) {
    __shared__ u16 lds[64][72];
    int gh = blockIdx.y, b = gh >> 3, h = gh & 7;
    int t0 = blockIdx.x * 64, tid = threadIdx.x;
#pragma unroll
    for (int it = 0; it < 2; it++) {
        int c = it * 256 + tid, tok = c >> 3, dq = c & 7;
        uint4 v = *(const uint4*)(qkv + (long)(b * TT + t0 + tok) * 1536 + 1024 + h * 64 + dq * 8);
        u16 s[8]; *(uint4*)s = v;
#pragma unroll
        for (int j = 0; j < 8; j++) lds[dq * 8 + j][tok] = s[j];
    }
    __syncthreads();
#pragma unroll
    for (int it = 0; it < 2; it++) {
        int c = it * 256 + tid, d = c >> 3, tq = c & 7;
        uint4 v = *(const uint4*)&lds[d][tq * 8];
        *(uint4*)(Vt + (long)gh * 98304 + (long)d * 1536 + t0 + tq * 8) = v;
    }
}

// ---------- VQ argmin (f64, 4-way ILP + float4 loads) + commit ----------
// Same math as proven version; accumulation split into 4 independent partial
// sums (f64 reassociation ~1e-16 — argmin indices unchanged).
__global__ __launch_bounds__(256) void k_vq(const float* __restrict__ xq, const float* __restrict__ cb,
                                            int* __restrict__ idx, float* __restrict__ commit) {
    __shared__ float xs[64];
    __shared__ double sd[256];
    __shared__ int si[256];
    int r = blockIdx.x, tid = threadIdx.x;
    if (tid < 64) xs[tid] = xq[(long)r * 64 + tid];
    __syncthreads();
    double bestd = 1e300; int bi = 0;
    for (int c = tid; c < CBN; c += 256) {
        const float4* crow = (const float4*)(cb + (long)c * 64);
        double s0 = 0.0, s1 = 0.0, s2 = 0.0, s3 = 0.0;
#pragma unroll
        for (int q = 0; q < 16; q++) {
            float4 cv = crow[q];
            float4 xv = *(const float4*)&xs[q * 4];
            float d0 = xv.x - cv.x, d1 = xv.y - cv.y, d2 = xv.z - cv.z, d3 = xv.w - cv.w;
            s0 = fma((double)d0, (double)d0, s0);
            s1 = fma((double)d1, (double)d1, s1);
            s2 = fma((double)d2, (double)d2, s2);
            s3 = fma((double)d3, (double)d3, s3);
        }
        double sacc = (s0 + s1) + (s2 + s3);
        if (sacc < bestd) { bestd = sacc; bi = c; }
    }
    sd[tid] = bestd; si[tid] = bi;
    __syncthreads();
    for (int off = 128; off > 0; off >>= 1) {
        if (tid < off) {
            if (sd[tid+off] < sd[tid] || (sd[tid+off] == sd[tid] && si[tid+off] < si[tid])) {
                sd[tid] = sd[tid+off]; si[tid] = si[tid+off];
            }
        }
        __syncthreads();
    }
    int win = si[0];
    if (tid == 0) idx[r] = win;
    if (tid < 64) {
        float diff = cb[(long)win * 64 + tid] - xs[tid];
        float sq = diff * diff;
        for (int off = 32; off > 0; off >>= 1) sq += __shfl_down(sq, off);
        if (tid == 0) atomicAdd(commit, sq);
    }
}

// ---------- softmax over 1500, f32 in -> bf16 out IN-PLACE (row-local) ----------
__global__ __launch_bounds__(256) void k_softmax_bf(float* __restrict__ sc) {
    float* row = sc + (long)blockIdx.y * 2304000 + (long)blockIdx.x * 1536;
    u16* prow = (u16*)row;                       // bf16 row over first half of f32 row
    int tid = threadIdx.x, lane = tid & 63, wid = tid >> 6;
    float v[6], mx = -1e30f;
#pragma unroll
    for (int l = 0; l < 6; l++) { int j = tid + l * 256; v[l] = (j < 1500) ? row[j] : -1e30f; mx = fmaxf(mx, v[l]); }
    for (int off = 32; off > 0; off >>= 1) mx = fmaxf(mx, __shfl_down(mx, off));
    __shared__ float sm[4];
    if (!lane) sm[wid] = mx;
    __syncthreads();
    mx = fmaxf(fmaxf(sm[0], sm[1]), fmaxf(sm[2], sm[3]));
    float s = 0.f;
#pragma unroll
    for (int l = 0; l < 6; l++) { int j = tid + l * 256; float e = (j < 1500) ? expf(v[l] - mx) : 0.f; v[l] = e; s += e; }
    for (int off = 32; off > 0; off >>= 1) s += __shfl_down(s, off);
    __shared__ float ssum[4];
    if (!lane) ssum[wid] = s;
    __syncthreads();
    s = ssum[0] + ssum[1] + ssum[2] + ssum[3];
    float inv = 1.0f / s;
#pragma unroll
    for (int l = 0; l < 6; l++) { int j = tid + l * 256; prow[j] = (j < 1500) ? f2b(v[l] * inv) : (u16)0; }
}

extern "C" void kernel_launch(void* const* d_in, const int* in_sizes, int n_in,
                              void* d_out, int out_size, void* d_ws, size_t ws_size,
                              hipStream_t stream) {
    const float* embs      = (const float*)d_in[0];
    const int*   mask      = (const int*)d_in[1];
    const float* mlp_ln_g  = (const float*)d_in[2];
    const float* mlp_ln_b  = (const float*)d_in[3];
    const float* mlp_w1    = (const float*)d_in[4];
    const float* mlp_b1    = (const float*)d_in[5];
    const float* mlp_w2    = (const float*)d_in[6];
    const float* mlp_b2    = (const float*)d_in[7];
    const float* proj_in_w = (const float*)d_in[8];
    const float* proj_in_b = (const float*)d_in[9];
    const float* codebook  = (const float*)d_in[10];
    const float* proj_out_w= (const float*)d_in[11];
    const float* proj_out_b= (const float*)d_in[12];
    const float* pos_emb   = (const float*)d_in[13];
    const float* attn_ln_g = (const float*)d_in[14];
    const float* attn_ln_b = (const float*)d_in[15];
    const float* wq = (const float*)d_in[16];
    const float* bq = (const float*)d_in[17];
    const float* wk = (const float*)d_in[18];
    const float* bk = (const float*)d_in[19];
    const float* wv = (const float*)d_in[20];
    const float* bv = (const float*)d_in[21];
    const float* wo = (const float*)d_in[22];
    const float* bo = (const float*)d_in[23];
    const float* ffn_ln_g = (const float*)d_in[24];
    const float* ffn_ln_b = (const float*)d_in[25];
    const float* ffn_w1   = (const float*)d_in[26];
    const float* ffn_b1   = (const float*)d_in[27];
    const float* ffn_w2   = (const float*)d_in[28];
    const float* ffn_b2   = (const float*)d_in[29];
    const float* ln_post_g= (const float*)d_in[30];
    const float* ln_post_b= (const float*)d_in[31];

    char* wsb = (char*)d_ws;
    float* ff1   = (float*)(wsb + B_FF1);
    float* x0    = (float*)(wsb + B_X0);
    float* h0    = (float*)(wsb + B_H0);     // h0 then x1
    float* sc    = (float*)(wsb + B_SC);
    u16*   ffbf  = (u16*)(wsb + B_FFBF);
    float* x4    = (float*)(wsb + B_X4);
    float* x2    = (float*)(wsb + B_X2);
    u16*   h2bf  = (u16*)(wsb + B_H2BF);     // then obf
    u16*   obf   = (u16*)(wsb + B_H2BF);
    u16*   qkv   = (u16*)(wsb + B_QKV);
    float* x3    = (float*)(wsb + B_X3);
    u16*   h3bf  = (u16*)(wsb + B_H3BF);
    u16*   Vt    = (u16*)(wsb + B_VT);
    float* xq    = (float*)(wsb + B_XQ);
    float* cbp   = (float*)(wsb + B_CBP);
    int*   idx   = (int*)(wsb + B_IDX);
    float* commit= (float*)(wsb + B_CMT);
    float* bqkv  = (float*)(wsb + B_BQKV);
    u16*   wqkvt = (u16*)(wsb + B_WQKVT);
    u16*   wot   = (u16*)(wsb + B_WOT);
    u16*   w1t   = (u16*)(wsb + B_W1T);
    u16*   w2t   = (u16*)(wsb + B_W2T);
    float* out   = (float*)d_out;

    hipMemsetAsync(commit, 0, sizeof(float), stream);

    // weight conversions (bf16, transposed to [N][K]) + bias concat
    k_wt<<<dim3(8, 8), 256, 0, stream>>>(wq, wqkvt,               512, 512);
    k_wt<<<dim3(8, 8), 256, 0, stream>>>(wk, wqkvt + 512 * 512,   512, 512);
    k_wt<<<dim3(8, 8), 256, 0, stream>>>(wv, wqkvt + 1024 * 512,  512, 512);
    k_wt<<<dim3(8, 8), 256, 0, stream>>>(wo, wot,                 512, 512);
    k_wt<<<dim3(8, 32), 256, 0, stream>>>(ffn_w1, w1t,            512, 2048);
    k_wt<<<dim3(32, 8), 256, 0, stream>>>(ffn_w2, w2t,            2048, 512);
    k_bcat<<<6, 256, 0, stream>>>(bq, bk, bv, bqkv);

    // ---- pre-VQ path (f32, numerically locked for argmin stability) ----
    k_ds_ln<<<N1, 128, 0, stream>>>(embs, mlp_ln_g, mlp_ln_b, x0, h0);
    k_gemm<64, 1><<<dim3(94, 16), 256, 0, stream>>>(h0, 512, mlp_w1, 2048, mlp_b1, nullptr, 0, ff1, 2048, N1, 2048, 512);
    k_gemm<64, 2><<<dim3(94, 4), 256, 0, stream>>>(ff1, 2048, mlp_w2, 512, mlp_b2, x0, 512, h0, 512, N1, 512, 2048);
    k_gemm<64, 0><<<dim3(94, 1), 256, 0, stream>>>(h0, 512, proj_in_w, 64, proj_in_b, nullptr, 0, xq, 64, N1, 64, 512);
    k_vq<<<N1, 256, 0, stream>>>(xq, codebook, idx, commit);
    k_gemm<64, 0><<<dim3(17, 4), 256, 0, stream>>>(codebook, 64, proj_out_w, 512, proj_out_b, nullptr, 0, cbp, 512, CBN, 512, 64);
    k_sel_pos_ln<<<N2, 128, 0, stream>>>(cbp, idx, mask, pos_emb, attn_ln_g, attn_ln_b, x2, h2bf);

    // ---- transformer block (bf16 MFMA) ----
    // QKV fused: [12000,1536] = h2bf @ [wq|wk|wv]
    k_bgemm<0, true><<<dim3(94, 12, 1), 256, 0, stream>>>(
        h2bf, 512, 0, wqkvt, 512, 0, bqkv, nullptr, 0, qkv, 1536, 0, N2, 1536, 512);
    k_vtrans<<<dim3(24, 64), 256, 0, stream>>>(qkv, Vt);

    for (int b = 0; b < BB; b++) {
        const u16* qb = qkv + (long)b * TT * 1536;
        // scores[h] = Q_h @ K_h^T   (f32 out, ldc 1536, K=64)
        k_bgemm<0, false><<<dim3(12, 12, 8), 256, 0, stream>>>(
            qb, 1536, 64, qb + 512, 1536, 64, nullptr, nullptr, 0,
            sc, 1536, 2304000L, TT, TT, 64);
        k_softmax_bf<<<dim3(TT, 8), 256, 0, stream>>>(sc);
        // O_h = P_h @ V_h^T  (P bf16 in-place over scores, lda 3072 shorts)
        k_bgemm<0, true><<<dim3(12, 1, 8), 256, 0, stream>>>(
            (const u16*)sc, 3072, 4608000L, Vt + (long)b * 8 * 98304, 1536, 98304L, nullptr, nullptr, 0,
            obf + (long)b * TT * 512, 512, 64L, TT, 64, 1536);
    }

    // WO + residual -> x3 (overwrites qkv slot; qkv dead)
    k_bgemm<2, false><<<dim3(94, 4, 1), 256, 0, stream>>>(
        obf, 512, 0, wot, 512, 0, bo, x2, 512, x3, 512, 0, N2, 512, 512);
    // FFN
    k_ln_tobf<<<N2, 128, 0, stream>>>(x3, ffn_ln_g, ffn_ln_b, h3bf);
    k_bgemm<1, true><<<dim3(94, 16, 1), 256, 0, stream>>>(
        h3bf, 512, 0, w1t, 512, 0, ffn_b1, nullptr, 0, ffbf, 2048, 0, N2, 2048, 512);
    k_bgemm<2, false><<<dim3(94, 4, 1), 256, 0, stream>>>(
        ffbf, 2048, 0, w2t, 2048, 0, ffn_b2, x3, 512, x4, 512, 0, N2, 512, 2048);
    // final LN + commit loss
    k_ln_out<<<N2, 128, 0, stream>>>(x4, ln_post_g, ln_post_b, out, commit);
}